// Round 10
// baseline (30859.247 us; speedup 1.0000x reference)
//
#include <hip/hip_runtime.h>
#include <hip/hip_fp16.h>
#include <math.h>

typedef unsigned int uint;

#define Bsz 64
#define Tt  1024
#define TH  512      // entities/slices < T/2, lens >= T/2 -> enc only needed for t < 512

// LDS byte offsets
#define XH_B    0        // x acts fp16 [2][256]
#define HCH_B   1024     // h acts fp16
#define HMH_B   2048     // hm acts fp16
#define HF_B    3072     // h f32 [2][256] (carry for B mult)
#define HMF_B   5120     // hm2 f32 (for E finalize)
#define GP_B    7168     // gparts f32 [2 mat][768 row][2 b] = 12288 B
#define RING_B  19456    // 8 waves x 4 slots x 4096 B = 131072
#define SMEM_B  150528

typedef _Float16 h2 __attribute__((ext_vector_type(2)));
#if defined(__has_builtin)
#if __has_builtin(__builtin_amdgcn_fdot2)
#define HAS_FDOT2 1
#endif
#endif

__device__ __forceinline__ float sigm(float x){ return 1.f/(1.f+expf(-x)); }

#define GLOAD16(g,l) __builtin_amdgcn_global_load_lds( \
    (const __attribute__((address_space(1))) void*)(g), \
    (__attribute__((address_space(3))) void*)(l), 16, 0, 0)
#define VM12 asm volatile("s_waitcnt vmcnt(12)":::"memory")
#define VM8  asm volatile("s_waitcnt vmcnt(8)":::"memory")
#define VM4  asm volatile("s_waitcnt vmcnt(4)":::"memory")
#define VM0  asm volatile("s_waitcnt vmcnt(0)":::"memory")
#define LG0  asm volatile("s_waitcnt lgkmcnt(0)":::"memory")
#define BAR  __builtin_amdgcn_s_barrier

__device__ __forceinline__ void dot2b(uint w, uint a0, uint a1, float& s0, float& s1){
  h2 wh = __builtin_bit_cast(h2, w);
#ifdef HAS_FDOT2
  s0 = __builtin_amdgcn_fdot2(wh, __builtin_bit_cast(h2,a0), s0, false);
  s1 = __builtin_amdgcn_fdot2(wh, __builtin_bit_cast(h2,a1), s1, false);
#else
  h2 x0 = __builtin_bit_cast(h2,a0), x1 = __builtin_bit_cast(h2,a1);
  s0 = fmaf((float)wh.x,(float)x0.x, fmaf((float)wh.y,(float)x0.y, s0));
  s1 = fmaf((float)wh.x,(float)x1.x, fmaf((float)wh.y,(float)x1.y, s1));
#endif
}

// Pack fp16 weights into per-(dir,wave) 4KB units with T21 cell swizzle.
// 32 stored units/region: [Q:0-3][R:4-7][G:8-31].
// Cell s decode: c8=s>>5, kq21=(s>>3)&3, g=(c8^kq21)&7, low3=(s&7)^g,
//   kq=(kq21<<1)|(low3>>2), c=low3&3, k0=kq*32+c*8; cell = 8 halfs W[...][k0..k0+8).
__global__ void pack_k(const float* __restrict__ Q, const float* __restrict__ R,
                       const float* __restrict__ Wih_f, const float* __restrict__ Whh_f,
                       const float* __restrict__ Wih_b, const float* __restrict__ Whh_b,
                       __half* __restrict__ Ws)
{
  int ci = blockIdx.x*256 + threadIdx.x;     // 16B cell, 131072 total
  if (ci >= 131072) return;
  int s = ci & 255;
  int unit = (ci>>8) & 31;
  int w = (ci>>13) & 7;
  int d = ci>>16;
  int c8 = s>>5, kq21 = (s>>3)&3;
  int g = (c8 ^ kq21) & 7;
  int low3 = (s&7) ^ g;
  int kq = (kq21<<1) | (low3>>2);
  int c = low3 & 3;
  int k0 = kq*32 + c*8;
  float v[8];
  if (unit < 8){
    const float* S = ((unit>=4)? R : Q) + d*65536;      // [k][j]
    int col = 32*w + 8*(unit&3) + c8;
    #pragma unroll
    for (int j=0;j<8;++j) v[j] = S[(k0+j)*256 + col];
  } else {
    int e = unit-8, mat = w&1, rb = w>>1;
    int row = 192*rb + 8*e + c8;
    const float* W = mat ? (d?Whh_b:Whh_f) : (d?Wih_b:Wih_f);  // [768][256]
    #pragma unroll
    for (int j=0;j<8;++j) v[j] = W[row*256 + k0 + j];
  }
  __half h8[8];
  #pragma unroll
  for (int j=0;j<8;++j) h8[j] = __float2half(v[j]);
  *(uint4*)(Ws + (size_t)ci*8) = *(uint4*)h8;
}

// One WG of 512 threads per (direction, batch-pair), dir grouped per XCD.
// Col-split phases: wave owns 32 mog cols / 192 GRU rows; full-k 4KB units,
// in-wave shfl reduce -> 6 barriers/step. 4-slot DMA ring, counted vmcnt.
__global__ __launch_bounds__(512) void scan_k(
    const int* __restrict__ sents, const int* __restrict__ lens,
    const float* __restrict__ emb,
    const float* __restrict__ bih_f, const float* __restrict__ bhh_f,
    const float* __restrict__ bih_b, const float* __restrict__ bhh_b,
    const __half* __restrict__ Wh, float* __restrict__ enc)
{
  extern __shared__ char smB[];

  const int bx = blockIdx.x;                 // 0..63
  const int dir  = ((bx & 7) >= 4) ? 1 : 0;  // dir constant per XCD residue class
  const int pair = (bx >> 3)*4 + (bx & 3);   // 0..31
  const int b0 = pair*2;
  const int tid = threadIdx.x;
  const int wv = tid >> 6, ln = tid & 63;
  const int c8 = ln >> 3, kq = ln & 7;
  const int cj = tid & 255, cb = tid >> 8;   // finalize (col, batch)
  const int matE = wv & 1, rbE = wv >> 1;    // E roles

  const char* wsbase = (const char*)Wh + ((size_t)(dir*8+wv))*32*4096;
  char* ring = smB + RING_B + wv*16384;
  const float* bih = dir ? bih_b : bih_f;
  const float* bhh = dir ? bhh_b : bhh_f;

  const int len0 = lens[b0], len1 = lens[b0+1];
  const int mylen = cb ? len1 : len0;
  const float bi_r = bih[cj], bi_z = bih[cj+256], bi_n = bih[cj+512];
  const float bh_r = bhh[cj], bh_z = bhh[cj+256], bh_n = bhh[cj+512];

  int nsteps, t, tstep;
  if (!dir){ nsteps = TH; t = 0; tstep = 1; }                         // fwd: t<512 observable
  else { int mx = max(len0,len1); nsteps = mx; t = mx-1; tstep = -1; } // bwd: h==0 while masked

  // per-lane constant offsets
  const int gsw = (c8 ^ (kq>>1)) & 7;
  int woff[4], aoff[4];
  #pragma unroll
  for (int c=0;c<4;++c){
    woff[c] = (((c8<<5) | ((kq>>1)<<3) | ((((kq&1)<<2)|c) ^ gsw))) * 16;
    aoff[c] = (((kq*4 + c) ^ (kq>>1))) * 16;          // b=0; +512 for b=1
  }
  const int wcol = 32*wv + 8*(kq&3) + c8;             // mog writer col
  const int wb_  = kq>>2;
  const int wr_h = ((wb_*32 + (wcol>>3)) ^ ((wcol>>6)&3))*16 + (wcol&7)*2;
  const int wr_f = (wb_*256 + wcol)*4;
  const int fin_h = ((cb*32 + (cj>>3)) ^ ((cj>>6)&3))*16 + (cj&7)*2;
  const int gpw = GP_B + ((matE*768 + 192*rbE + c8)*2 + kq)*4;   // kq<2 writers
  const int colbase = 32*wv + c8;

  auto ISSUE = [&](int u, int slot){
    const char* gp = wsbase + (size_t)u*4096 + ln*16;
    char* lp = ring + slot*4096;
    GLOAD16(gp, lp); GLOAD16(gp+1024, lp+1024);
    GLOAD16(gp+2048, lp+2048); GLOAD16(gp+3072, lp+3072);
  };
  auto dot4 = [&](const uint4& W, const uint4& A0c, const uint4& A1c, float& a0, float& a1){
    dot2b(W.x, A0c.x, A1c.x, a0, a1);
    dot2b(W.y, A0c.y, A1c.y, a0, a1);
    dot2b(W.z, A0c.z, A1c.z, a0, a1);
    dot2b(W.w, A0c.w, A1c.w, a0, a1);
  };
  auto red8 = [&](float& a){
    a += __shfl_xor(a,1); a += __shfl_xor(a,2); a += __shfl_xor(a,4);
  };
  // One mog phase: acts at actB, consume 4 units issuing issUB+u, gate into mult.
  auto mogphase = [&](int actB, int issUB, float (&mult)[4][2], int dstB, bool alsoF32){
    uint4 A0[4], A1[4];
    #pragma unroll
    for (int c=0;c<4;++c){
      A0[c] = *(const uint4*)(smB + actB +       aoff[c]);
      A1[c] = *(const uint4*)(smB + actB + 512 + aoff[c]);
    }
    #pragma unroll
    for (int u=0;u<4;++u){
      VM12;
      const char* wb = ring + u*4096;
      uint4 W0 = *(const uint4*)(wb + woff[0]);
      uint4 W1 = *(const uint4*)(wb + woff[1]);
      uint4 W2 = *(const uint4*)(wb + woff[2]);
      uint4 W3 = *(const uint4*)(wb + woff[3]);
      LG0;
      ISSUE(issUB + u, u);
      float a0 = 0.f, a1 = 0.f;
      dot4(W0, A0[0], A1[0], a0, a1);
      dot4(W1, A0[1], A1[1], a0, a1);
      dot4(W2, A0[2], A1[2], a0, a1);
      dot4(W3, A0[3], A1[3], a0, a1);
      red8(a0); red8(a1);
      mult[u][0] = 2.f*sigm(a0)*mult[u][0];
      mult[u][1] = 2.f*sigm(a1)*mult[u][1];
    }
    float wval = mult[kq&3][kq>>2];
    *(__half*)(smB + dstB + wr_h) = (__half)wval;
    if (alsoF32) *(float*)(smB + HMF_B + wr_f) = wval;
    LG0; BAR();
  };

  // init
  if (tid < 256) *((uint*)(smB + HCH_B) + tid) = 0u;
  if (tid < 512) *((float*)(smB + HF_B) + tid) = 0.f;
  ISSUE(0,0); ISSUE(1,1); ISSUE(2,2); ISSUE(3,3);
  float hprev = 0.f;
  float xch[4][2], hmch[4][2];
  LG0; BAR();

  for (int s=0; s<nsteps; ++s, t+=tstep){
    const bool lastst = (s == nsteps-1);
    const int tk0 = sents[b0*Tt + t];
    const int tk1 = sents[(b0+1)*Tt + t];
    #pragma unroll
    for (int u=0;u<4;++u){
      xch[u][0] = emb[(size_t)tk0*256 + colbase + 8*u];
      xch[u][1] = emb[(size_t)tk1*256 + colbase + 8*u];
    }
    // A: x1 = 2sig(h@Q)*x0            (consume Q0-3, issue R0-3)
    mogphase(HCH_B, 4, xch, XH_B, false);
    // B: hm1 = 2sig(x1@R)*h           (consume R0-3, issue Q0-3)
    #pragma unroll
    for (int u=0;u<4;++u){
      hmch[u][0] = *(const float*)(smB + HF_B + (colbase + 8*u)*4);
      hmch[u][1] = *(const float*)(smB + HF_B + (256 + colbase + 8*u)*4);
    }
    mogphase(XH_B, 0, hmch, HMH_B, false);
    // C: x2 = 2sig(hm1@Q)*x1          (consume Q0-3, issue R0-3)
    mogphase(HMH_B, 4, xch, XH_B, false);
    // D: hm2 = 2sig(x2@R)*hm1 (+f32)  (consume R0-3, issue G0-3)
    mogphase(XH_B, 8, hmch, HMH_B, true);

    // E: GRU — wave (matE, rbE) computes its 192 rows; 24 units.
    {
      const int eactB = matE ? HMH_B : XH_B;
      uint4 E0[4], E1[4];
      #pragma unroll
      for (int c=0;c<4;++c){
        E0[c] = *(const uint4*)(smB + eactB +       aoff[c]);
        E1[c] = *(const uint4*)(smB + eactB + 512 + aoff[c]);
      }
      #pragma unroll
      for (int e=0;e<24;++e){
        if (lastst && e>=21){ if (e==21){VM8;} else if (e==22){VM4;} else {VM0;} }
        else VM12;
        const char* wb = ring + ((16+e)&3)*4096;
        uint4 W0 = *(const uint4*)(wb + woff[0]);
        uint4 W1 = *(const uint4*)(wb + woff[1]);
        uint4 W2 = *(const uint4*)(wb + woff[2]);
        uint4 W3 = *(const uint4*)(wb + woff[3]);
        LG0;
        if (!(lastst && e>=20)) ISSUE((e<20) ? (12+e) : (e-20), (16+e)&3);
        float a0 = 0.f, a1 = 0.f;
        dot4(W0, E0[0], E1[0], a0, a1);
        dot4(W1, E0[1], E1[1], a0, a1);
        dot4(W2, E0[2], E1[2], a0, a1);
        dot4(W3, E0[3], E1[3], a0, a1);
        red8(a0); red8(a1);
        if (kq == 0) *(float*)(smB + gpw + e*64) = a0;
        else if (kq == 1) *(float*)(smB + gpw + e*64) = a1;
      }
    }
    LG0; BAR();
    // finalize GRU: thread (cj, cb)
    {
      float gir = *(const float*)(smB + GP_B + (( cj          )*2 + cb)*4);
      float giz = *(const float*)(smB + GP_B + ((256 + cj     )*2 + cb)*4);
      float gin = *(const float*)(smB + GP_B + ((512 + cj     )*2 + cb)*4);
      float ghr = *(const float*)(smB + GP_B + ((768 + cj     )*2 + cb)*4);
      float ghz = *(const float*)(smB + GP_B + ((768+256 + cj )*2 + cb)*4);
      float ghn = *(const float*)(smB + GP_B + ((768+512 + cj )*2 + cb)*4);
      float hm2v = *(const float*)(smB + HMF_B + (cb*256+cj)*4);
      float r = sigm(gir + bi_r + ghr + bh_r);
      float z = sigm(giz + bi_z + ghz + bh_z);
      float n = tanhf(gin + bi_n + r*(ghn + bh_n));
      float uu = (1.f - z)*n + z*hm2v;
      bool m = (t < mylen);
      float hnew = m ? uu : hprev;
      hprev = hnew;
      *(__half*)(smB + HCH_B + fin_h) = (__half)hnew;
      *(float*)(smB + HF_B + (cb*256+cj)*4) = hnew;
      if (m && t < TH)
        atomicAdd(&enc[((size_t)(b0+cb)*TH + t)*256 + cj], uu);
    }
    LG0; BAR();
  }
}

// One WG per batch element. Reproduces gate_attention + attention + dense exactly.
__global__ __launch_bounds__(256) void epi_k(
    const float* __restrict__ enc,
    const int* __restrict__ entities, const int* __restrict__ slices,
    const float* __restrict__ slice_lens,
    const int* __restrict__ entity_masks, const int* __restrict__ slice_masks,
    const float* __restrict__ ent_W, const float* __restrict__ ent_b,
    const float* __restrict__ att_w,
    const float* __restrict__ dense_W, const float* __restrict__ dense_b,
    float* __restrict__ out)
{
    const int b = blockIdx.x;
    const int j = threadIdx.x;
    const int wave = j >> 6, lane = j & 63;

    __shared__ float ee[8][256];
    __shared__ float p[256];
    __shared__ float rela[256];
    __shared__ float sc[264];
    __shared__ float red[4];
    __shared__ float aw[256];
    __shared__ int   spos[256];

    aw[j]   = att_w[j];
    spos[j] = slices[b * 256 + j];
    #pragma unroll
    for (int e = 0; e < 8; ++e)
        ee[e][j] = enc[((size_t)b * TH + entities[b * 8 + e]) * 256 + j];
    __syncthreads();

    float entWj = ent_W[j];
    for (int e = 0; e < 8; ++e) {
        float v = ee[e][j] * entWj;
        #pragma unroll
        for (int o = 32; o > 0; o >>= 1) v += __shfl_down(v, o);
        if (lane == 0) red[wave] = v;
        __syncthreads();
        if (j == 0) sc[e] = red[0] + red[1] + red[2] + red[3] + ent_b[0];
        __syncthreads();
    }
    float mx = -INFINITY;
    float ewv[8];
    #pragma unroll
    for (int e = 0; e < 8; ++e) {
        float v = entity_masks[b * 8 + e] ? sc[e] : -INFINITY;
        ewv[e] = v; mx = fmaxf(mx, v);
    }
    float den = 0.f;
    #pragma unroll
    for (int e = 0; e < 8; ++e) {
        ewv[e] = entity_masks[b * 8 + e] ? expf(ewv[e] - mx) : 0.f;
        den += ewv[e];
    }
    float accp = 0.f;
    #pragma unroll
    for (int e = 0; e < 8; ++e) accp += (ewv[e] / den) * ee[e][j];
    p[j] = tanhf(accp);
    __syncthreads();

    for (int s0 = wave; s0 < 256; s0 += 4) {
        const float* row = enc + ((size_t)b * TH + spos[s0]) * 256;
        float v = 0.f;
        #pragma unroll
        for (int i = 0; i < 4; ++i) { int c = lane + 64 * i; v += row[c] * p[c]; }
        #pragma unroll
        for (int o = 32; o > 0; o >>= 1) v += __shfl_down(v, o);
        if (lane == 0) sc[s0] = v;
    }
    __syncthreads();

    float sl  = slice_lens[b];
    int   smk = slice_masks[b * 256 + j];
    float wv  = smk ? sc[j] : -INFINITY;
    float bm = wv;
    #pragma unroll
    for (int o = 32; o > 0; o >>= 1) bm = fmaxf(bm, __shfl_down(bm, o));
    __syncthreads();
    if (lane == 0) red[wave] = bm;
    __syncthreads();
    bm = fmaxf(fmaxf(red[0], red[1]), fmaxf(red[2], red[3]));
    float ex = smk ? expf(wv - bm) : 0.f;
    float sm2 = ex;
    #pragma unroll
    for (int o = 32; o > 0; o >>= 1) sm2 += __shfl_down(sm2, o);
    __syncthreads();
    if (lane == 0) red[wave] = sm2;
    __syncthreads();
    sm2 = red[0] + red[1] + red[2] + red[3];
    float ww = ex / sm2 * sl;
    float rl = (ww > 0.05f) ? (ww / sl) : 0.f;   // BETA = 0.05
    float rm = rl;
    #pragma unroll
    for (int o = 32; o > 0; o >>= 1) rm = fmaxf(rm, __shfl_down(rm, o));
    __syncthreads();
    if (lane == 0) red[wave] = rm;
    __syncthreads();
    rm = fmaxf(fmaxf(red[0], red[1]), fmaxf(red[2], red[3]));
    rl = rl / rm;
    rela[j] = rl;
    __syncthreads();

    for (int n = wave; n < 264; n += 4) {
        float v = 0.f;
        if (n < 8) {
            #pragma unroll
            for (int i = 0; i < 4; ++i) { int c = lane + 64 * i; v += tanhf(ee[n][c]) * aw[c]; }
        } else {
            int s0 = n - 8;
            const float* row = enc + ((size_t)b * TH + spos[s0]) * 256;
            float rl2 = rela[s0];
            #pragma unroll
            for (int i = 0; i < 4; ++i) { int c = lane + 64 * i; v += tanhf(rl2 * row[c]) * aw[c]; }
        }
        #pragma unroll
        for (int o = 32; o > 0; o >>= 1) v += __shfl_down(v, o);
        if (lane == 0) sc[n] = v;
    }
    __syncthreads();

    float a1 = sc[j];       a1 = (a1 == 0.f) ? -INFINITY : a1;
    float a2 = (j < 8) ? sc[256 + j] : -INFINITY;
    if (a2 == 0.f) a2 = -INFINITY;
    float am = fmaxf(a1, a2);
    #pragma unroll
    for (int o = 32; o > 0; o >>= 1) am = fmaxf(am, __shfl_down(am, o));
    __syncthreads();
    if (lane == 0) red[wave] = am;
    __syncthreads();
    am = fmaxf(fmaxf(red[0], red[1]), fmaxf(red[2], red[3]));
    float e1 = (a1 == -INFINITY) ? 0.f : expf(a1 - am);
    float e2 = (a2 == -INFINITY) ? 0.f : expf(a2 - am);
    float esum = e1 + e2;
    #pragma unroll
    for (int o = 32; o > 0; o >>= 1) esum += __shfl_down(esum, o);
    __syncthreads();
    if (lane == 0) red[wave] = esum;
    __syncthreads();
    esum = red[0] + red[1] + red[2] + red[3];
    __syncthreads();
    sc[j] = e1 / esum;
    if (j < 8) sc[256 + j] = e2 / esum;
    __syncthreads();

    float att = 0.f;
    #pragma unroll
    for (int n = 0; n < 8; ++n) att += sc[n] * ee[n][j];
    for (int s0 = 0; s0 < 256; ++s0) {
        float scn = sc[8 + s0];
        if (scn > 0.f)
            att += scn * rela[s0] * enc[((size_t)b * TH + spos[s0]) * 256 + j];
    }
    float ta = tanhf(att);

    for (int l = 0; l < 19; ++l) {
        float v = ta * dense_W[l * 256 + j];
        #pragma unroll
        for (int o = 32; o > 0; o >>= 1) v += __shfl_down(v, o);
        __syncthreads();
        if (lane == 0) red[wave] = v;
        __syncthreads();
        if (j == 0) out[b * 19 + l] = red[0] + red[1] + red[2] + red[3] + dense_b[l];
    }
}

extern "C" void kernel_launch(void* const* d_in, const int* in_sizes, int n_in,
                              void* d_out, int out_size, void* d_ws, size_t ws_size,
                              hipStream_t stream) {
    (void)in_sizes; (void)n_in; (void)out_size; (void)ws_size;
    const int*   sents        = (const int*)d_in[0];
    const int*   lens         = (const int*)d_in[1];
    const int*   entities     = (const int*)d_in[2];
    const int*   slices       = (const int*)d_in[3];
    const float* slice_lens   = (const float*)d_in[4];
    const int*   entity_masks = (const int*)d_in[5];
    const int*   slice_masks  = (const int*)d_in[6];
    const float* emb          = (const float*)d_in[7];
    const float* Q            = (const float*)d_in[8];
    const float* R            = (const float*)d_in[9];
    const float* Wih_f        = (const float*)d_in[10];
    const float* Whh_f        = (const float*)d_in[11];
    const float* bih_f        = (const float*)d_in[12];
    const float* bhh_f        = (const float*)d_in[13];
    const float* Wih_b        = (const float*)d_in[14];
    const float* Whh_b        = (const float*)d_in[15];
    const float* bih_b        = (const float*)d_in[16];
    const float* bhh_b        = (const float*)d_in[17];
    const float* ent_W        = (const float*)d_in[18];
    const float* ent_b        = (const float*)d_in[19];
    const float* att_w        = (const float*)d_in[20];
    const float* dense_W      = (const float*)d_in[21];
    const float* dense_b      = (const float*)d_in[22];

    // ws: enc [64][512][256] f32 (33.5MB) | Ws 2MB fp16 streams
    float*  enc = (float*)d_ws;
    __half* Ws  = (__half*)(enc + (size_t)Bsz * TH * 256);

    hipFuncSetAttribute(reinterpret_cast<const void*>(scan_k),
                        hipFuncAttributeMaxDynamicSharedMemorySize, SMEM_B);

    hipMemsetAsync(enc, 0, (size_t)Bsz * TH * 256 * sizeof(float), stream);
    pack_k<<<512, 256, 0, stream>>>(Q, R, Wih_f, Whh_f, Wih_b, Whh_b, Ws);
    scan_k<<<64, 512, SMEM_B, stream>>>(sents, lens, emb,
                                        bih_f, bhh_f, bih_b, bhh_b,
                                        Ws, enc);
    epi_k<<<64, 256, 0, stream>>>(enc, entities, slices, slice_lens,
                                  entity_masks, slice_masks, ent_W, ent_b,
                                  att_w, dense_W, dense_b, (float*)d_out);
}

// Round 11
// 11454.288 us; speedup vs baseline: 2.6941x; 2.6941x over previous
//
#include <hip/hip_runtime.h>
#include <hip/hip_fp16.h>
#include <math.h>

typedef unsigned int uint;

#define Bsz 64
#define Tt  1024
#define TH  512      // entities/slices < T/2, lens >= T/2 -> enc only needed for t < 512

// LDS float offsets (half-offsets into smH: xs 0, hcs 512, hms 1024 -> bytes 0..3071)
#define HMF   1280   // float[512] hm2 f32 (for E finalize)
#define PARTF 1792   // 12288 floats (mog 8x512 / gru 8x1536 overlay)
#define SMEMF 14080  // 56320 B

typedef _Float16 h2 __attribute__((ext_vector_type(2)));
#if defined(__has_builtin)
#if __has_builtin(__builtin_amdgcn_fdot2)
#define HAS_FDOT2 1
#endif
#endif

__device__ __forceinline__ float sigm(float x){ return 1.f/(1.f+expf(-x)); }

#define LG0  asm volatile("s_waitcnt lgkmcnt(0)":::"memory")
#define BAR  __builtin_amdgcn_s_barrier

__device__ __forceinline__ void dot2b(uint w, uint a0, uint a1, float& s0, float& s1){
  h2 wh = __builtin_bit_cast(h2, w);
#ifdef HAS_FDOT2
  s0 = __builtin_amdgcn_fdot2(wh, __builtin_bit_cast(h2,a0), s0, false);
  s1 = __builtin_amdgcn_fdot2(wh, __builtin_bit_cast(h2,a1), s1, false);
#else
  h2 x0 = __builtin_bit_cast(h2,a0), x1 = __builtin_bit_cast(h2,a1);
  s0 = fmaf((float)wh.x,(float)x0.x, fmaf((float)wh.y,(float)x0.y, s0));
  s1 = fmaf((float)wh.x,(float)x1.x, fmaf((float)wh.y,(float)x1.y, s1));
#endif
}

// Pack all weights to fp16 in per-(dir,wave) consumption-ordered 4KB units. (R9 layout)
// QH [0,131072) | RH [131072,262144) | GH [262144,1048576) (halfs).
// Q/R unit u (of 4, wave w): cell c<256 = col c, halfs jj<8 = W[32w+8u+jj][c].
// G unit e=u8*3+g (of 24, wave w: mat=w&1, ks=w>>1): cell c = W[g*256+c][64ks+8u8+jj].
__global__ void pack_k(const float* __restrict__ Q, const float* __restrict__ R,
                       const float* __restrict__ Wih_f, const float* __restrict__ Whh_f,
                       const float* __restrict__ Wih_b, const float* __restrict__ Whh_b,
                       __half* __restrict__ Wh)
{
  int ci = blockIdx.x*256 + threadIdx.x;       // 16B cell index, 131072 total
  if (ci >= 131072) return;
  float v[8];
  if (ci < 32768){
    bool isR = ci >= 16384;
    int c0 = ci & 16383;
    int c = c0 & 255;
    int rest = c0 >> 8;                        // (d*8+w)*4+u
    int u = rest & 3, dw = rest >> 2;
    int w = dw & 7, d = dw >> 3;
    const float* S = (isR ? R : Q) + d*65536;  // [k][j]
    int k0 = 32*w + 8*u;
    #pragma unroll
    for (int j=0;j<8;++j) v[j] = S[(k0+j)*256 + c];
  } else {
    int c0 = ci - 32768;                       // 98304 cells
    int c = c0 & 255;
    int rest = c0 >> 8;                        // (d*8+w)*24+e
    int e = rest % 24, dw = rest / 24;
    int w = dw & 7, d = dw >> 3;
    int mat = w & 1, ks = w >> 1;
    int u8 = e / 3, g = e % 3;
    const float* W = mat ? (d? Whh_b : Whh_f) : (d? Wih_b : Wih_f);  // [768][256]
    const float* row = W + (size_t)(g*256 + c)*256 + (64*ks + 8*u8);
    #pragma unroll
    for (int j=0;j<8;++j) v[j] = row[j];
  }
  __half h8[8];
  #pragma unroll
  for (int j=0;j<8;++j) h8[j] = __float2half(v[j]);
  *(uint4*)(Wh + (size_t)ci*8) = *(uint4*)h8;
}

// One WG of 512 threads per (direction, batch-pair), dir grouped per XCD.
// fp16 weights load global->VGPR directly (no LDS round-trip): in-phase 4xuint4
// double buffer + persistent P[4] primed with next phase's unit0 across barriers.
// Carry chain (h, x1, hm1, hm2) stays f32 in registers.
__global__ __launch_bounds__(512) void scan_k(
    const int* __restrict__ sents, const int* __restrict__ lens,
    const float* __restrict__ emb,
    const float* __restrict__ bih_f, const float* __restrict__ bhh_f,
    const float* __restrict__ bih_b, const float* __restrict__ bhh_b,
    const __half* __restrict__ Wh, float* __restrict__ enc)
{
  extern __shared__ float sm[];
  __half* smH = (__half*)sm;

  const int bx = blockIdx.x;                 // 0..63
  const int dir  = ((bx & 7) >= 4) ? 1 : 0;  // dir constant per XCD residue class
  const int pair = (bx >> 3)*4 + (bx & 3);   // 0..31
  const int b0 = pair*2;
  const int tid = threadIdx.x;
  const int wv = tid >> 6, ln = tid & 63;
  const int cj = tid & 255, cb = tid >> 8;   // finalize (col, batch)
  const int matE = wv & 1, ksE = wv >> 1;    // GRU wave roles

  const __half* QB = Wh + (size_t)((dir*8+wv)*4)*2048;
  const __half* RB = Wh + 131072 + (size_t)((dir*8+wv)*4)*2048;
  const __half* GB = Wh + 262144 + (size_t)((dir*8+wv)*24)*2048;
  const float* bih = dir ? bih_b : bih_f;
  const float* bhh = dir ? bhh_b : bhh_f;

  const int len0 = lens[b0], len1 = lens[b0+1];
  const int mylen = cb ? len1 : len0;
  const float bi_r = bih[cj], bi_z = bih[cj+256], bi_n = bih[cj+512];
  const float bh_r = bhh[cj], bh_z = bhh[cj+256], bh_n = bhh[cj+512];

  int nsteps, t, tstep;
  if (!dir){ nsteps = TH; t = 0; tstep = 1; }                        // fwd: t<512 observable
  else { int mx = max(len0,len1); nsteps = mx; t = mx-1; tstep = -1; } // bwd: h==0 while masked

  smH[512 + tid] = (__half)0.f;              // hcs zero (512 halfs)

  uint4 P0, P1, P2, P3;                      // persistent next-unit prefetch
  { const uint4* p = (const uint4*)QB;
    P0 = p[ln]; P1 = p[ln+64]; P2 = p[ln+128]; P3 = p[ln+192]; }

  auto dot4 = [&](const uint4& W, const uint4& A0, const uint4& A1, float& a0, float& a1){
    dot2b(W.x, A0.x, A1.x, a0, a1);
    dot2b(W.y, A0.y, A1.y, a0, a1);
    dot2b(W.z, A0.z, A1.z, a0, a1);
    dot2b(W.w, A0.w, A1.w, a0, a1);
  };

  // 4 units of a mog phase; at the end preload next phase's unit0 into P.
  auto mog_part = [&](int actsHO, const __half* ub, const __half* nextb){
    float2 acc[4];
    acc[0]=acc[1]=acc[2]=acc[3]=make_float2(0.f,0.f);
    uint4 Wc0=P0, Wc1=P1, Wc2=P2, Wc3=P3;
    #pragma unroll
    for (int u=0; u<4; ++u){
      uint4 Wn0,Wn1,Wn2,Wn3;
      { const uint4* p = (const uint4*)((u<3) ? (ub + (u+1)*2048) : nextb);
        Wn0=p[ln]; Wn1=p[ln+64]; Wn2=p[ln+128]; Wn3=p[ln+192]; }
      const int k8 = 4*wv + u;
      const uint4 a0 = *(const uint4*)(smH + actsHO + k8*8);
      const uint4 a1 = *(const uint4*)(smH + actsHO + 256 + k8*8);
      dot4(Wc0, a0, a1, acc[0].x, acc[0].y);
      dot4(Wc1, a0, a1, acc[1].x, acc[1].y);
      dot4(Wc2, a0, a1, acc[2].x, acc[2].y);
      dot4(Wc3, a0, a1, acc[3].x, acc[3].y);
      if (u < 3){ Wc0=Wn0; Wc1=Wn1; Wc2=Wn2; Wc3=Wn3; }
      else      { P0=Wn0; P1=Wn1; P2=Wn2; P3=Wn3; }
    }
    #pragma unroll
    for (int q=0;q<4;++q)
      *(float2*)(sm + PARTF + wv*512 + (ln+64*q)*2) = acc[q];
  };
  // finalize mog (thread = (cj,cb)): sum 8 partials, gate, store fp16 (+opt f32) act.
  auto mog_fin = [&](float mult, int dstHO, bool alsoF32)->float{
    float ssum = 0.f;
    #pragma unroll
    for (int p=0;p<8;++p) ssum += sm[PARTF + p*512 + cj*2 + cb];
    float val = 2.f*sigm(ssum)*mult;
    smH[dstHO + cb*256 + cj] = (__half)val;
    if (alsoF32) sm[HMF + cb*256 + cj] = val;
    return val;
  };

  float hprev = 0.f, x1 = 0.f, hm1 = 0.f, hm2 = 0.f;
  LG0; BAR();

  for (int s=0; s<nsteps; ++s, t+=tstep){
    int tok = sents[(b0+cb)*Tt + t];
    float x0 = emb[(size_t)tok*256 + cj];

    // A: x1 = 2sig(h@Q)*x0       (consume Q, prime R)
    mog_part(512, QB, RB);          LG0; BAR();
    x1 = mog_fin(x0, 0, false);     LG0; BAR();
    // B: hm1 = 2sig(x1@R)*h      (consume R, prime Q)
    mog_part(0, RB, QB);            LG0; BAR();
    hm1 = mog_fin(hprev, 1024, false); LG0; BAR();
    // C: x2 = 2sig(hm1@Q)*x1     (consume Q, prime R)
    mog_part(1024, QB, RB);         LG0; BAR();
    x1 = mog_fin(x1, 0, false);     LG0; BAR();      // x1 now holds x2
    // D: hm2 = 2sig(x2@R)*hm1    (consume R, prime G)
    mog_part(0, RB, GB);            LG0; BAR();
    hm2 = mog_fin(hm1, 1024, true); LG0; BAR();

    // E: GRU — gi = x2@Wih^T (even waves), gh = hm2@Whh^T (odd); fp16 acts, dot2.
    {
      const int AFh = matE ? 1024 : 0;
      float2 ag[12];
      #pragma unroll
      for (int i=0;i<12;++i) ag[i] = make_float2(0.f,0.f);
      uint4 Wc0=P0, Wc1=P1, Wc2=P2, Wc3=P3;
      for (int e=0;e<24;++e){
        uint4 Wn0,Wn1,Wn2,Wn3;
        { const uint4* p = (const uint4*)((e<23) ? (GB + (e+1)*2048) : QB);
          Wn0=p[ln]; Wn1=p[ln+64]; Wn2=p[ln+128]; Wn3=p[ln+192]; }
        const int u8 = e/3, g = e - 3*u8;
        const int kb = 64*ksE + 8*u8;
        const uint4 a0 = *(const uint4*)(smH + AFh + kb);
        const uint4 a1 = *(const uint4*)(smH + AFh + 256 + kb);
        dot4(Wc0, a0, a1, ag[g*4+0].x, ag[g*4+0].y);
        dot4(Wc1, a0, a1, ag[g*4+1].x, ag[g*4+1].y);
        dot4(Wc2, a0, a1, ag[g*4+2].x, ag[g*4+2].y);
        dot4(Wc3, a0, a1, ag[g*4+3].x, ag[g*4+3].y);
        if (e < 23){ Wc0=Wn0; Wc1=Wn1; Wc2=Wn2; Wc3=Wn3; }
        else       { P0=Wn0; P1=Wn1; P2=Wn2; P3=Wn3; }   // next step's Q0
      }
      #pragma unroll
      for (int g=0;g<3;++g)
        #pragma unroll
        for (int q=0;q<4;++q)
          *(float2*)(sm + PARTF + wv*1536 + (g*256 + ln + 64*q)*2) = ag[g*4+q];
    }
    LG0; BAR();
    // finalize GRU: thread (cj, cb)
    {
      float gi[3], gh[3];
      #pragma unroll
      for (int g=0; g<3; ++g){
        float si = 0.f, sh = 0.f;
        #pragma unroll
        for (int p=0;p<4;++p){
          si += sm[PARTF + (p*2+0)*1536 + (g*256+cj)*2 + cb];
          sh += sm[PARTF + (p*2+1)*1536 + (g*256+cj)*2 + cb];
        }
        gi[g] = si; gh[g] = sh;
      }
      float r = sigm(gi[0]+bi_r + gh[0]+bh_r);
      float z = sigm(gi[1]+bi_z + gh[1]+bh_z);
      float n = tanhf(gi[2]+bi_n + r*(gh[2]+bh_n));
      float hm2v = sm[HMF + cb*256 + cj];
      float uu = (1.f - z)*n + z*hm2v;
      bool m = (t < mylen);
      float hnew = m ? uu : hprev;
      hprev = hnew;
      smH[512 + cb*256 + cj] = (__half)hnew;
      if (m && t < TH)
        atomicAdd(&enc[((size_t)(b0+cb)*TH + t)*256 + cj], uu);
    }
    LG0; BAR();
    (void)hm2;
  }
}

// One WG per batch element. Reproduces gate_attention + attention + dense exactly.
__global__ __launch_bounds__(256) void epi_k(
    const float* __restrict__ enc,
    const int* __restrict__ entities, const int* __restrict__ slices,
    const float* __restrict__ slice_lens,
    const int* __restrict__ entity_masks, const int* __restrict__ slice_masks,
    const float* __restrict__ ent_W, const float* __restrict__ ent_b,
    const float* __restrict__ att_w,
    const float* __restrict__ dense_W, const float* __restrict__ dense_b,
    float* __restrict__ out)
{
    const int b = blockIdx.x;
    const int j = threadIdx.x;
    const int wave = j >> 6, lane = j & 63;

    __shared__ float ee[8][256];
    __shared__ float p[256];
    __shared__ float rela[256];
    __shared__ float sc[264];
    __shared__ float red[4];
    __shared__ float aw[256];
    __shared__ int   spos[256];

    aw[j]   = att_w[j];
    spos[j] = slices[b * 256 + j];
    #pragma unroll
    for (int e = 0; e < 8; ++e)
        ee[e][j] = enc[((size_t)b * TH + entities[b * 8 + e]) * 256 + j];
    __syncthreads();

    float entWj = ent_W[j];
    for (int e = 0; e < 8; ++e) {
        float v = ee[e][j] * entWj;
        #pragma unroll
        for (int o = 32; o > 0; o >>= 1) v += __shfl_down(v, o);
        if (lane == 0) red[wave] = v;
        __syncthreads();
        if (j == 0) sc[e] = red[0] + red[1] + red[2] + red[3] + ent_b[0];
        __syncthreads();
    }
    float mx = -INFINITY;
    float ewv[8];
    #pragma unroll
    for (int e = 0; e < 8; ++e) {
        float v = entity_masks[b * 8 + e] ? sc[e] : -INFINITY;
        ewv[e] = v; mx = fmaxf(mx, v);
    }
    float den = 0.f;
    #pragma unroll
    for (int e = 0; e < 8; ++e) {
        ewv[e] = entity_masks[b * 8 + e] ? expf(ewv[e] - mx) : 0.f;
        den += ewv[e];
    }
    float accp = 0.f;
    #pragma unroll
    for (int e = 0; e < 8; ++e) accp += (ewv[e] / den) * ee[e][j];
    p[j] = tanhf(accp);
    __syncthreads();

    for (int s0 = wave; s0 < 256; s0 += 4) {
        const float* row = enc + ((size_t)b * TH + spos[s0]) * 256;
        float v = 0.f;
        #pragma unroll
        for (int i = 0; i < 4; ++i) { int c = lane + 64 * i; v += row[c] * p[c]; }
        #pragma unroll
        for (int o = 32; o > 0; o >>= 1) v += __shfl_down(v, o);
        if (lane == 0) sc[s0] = v;
    }
    __syncthreads();

    float sl  = slice_lens[b];
    int   smk = slice_masks[b * 256 + j];
    float wv  = smk ? sc[j] : -INFINITY;
    float bm = wv;
    #pragma unroll
    for (int o = 32; o > 0; o >>= 1) bm = fmaxf(bm, __shfl_down(bm, o));
    __syncthreads();
    if (lane == 0) red[wave] = bm;
    __syncthreads();
    bm = fmaxf(fmaxf(red[0], red[1]), fmaxf(red[2], red[3]));
    float ex = smk ? expf(wv - bm) : 0.f;
    float sm2 = ex;
    #pragma unroll
    for (int o = 32; o > 0; o >>= 1) sm2 += __shfl_down(sm2, o);
    __syncthreads();
    if (lane == 0) red[wave] = sm2;
    __syncthreads();
    sm2 = red[0] + red[1] + red[2] + red[3];
    float ww = ex / sm2 * sl;
    float rl = (ww > 0.05f) ? (ww / sl) : 0.f;   // BETA = 0.05
    float rm = rl;
    #pragma unroll
    for (int o = 32; o > 0; o >>= 1) rm = fmaxf(rm, __shfl_down(rm, o));
    __syncthreads();
    if (lane == 0) red[wave] = rm;
    __syncthreads();
    rm = fmaxf(fmaxf(red[0], red[1]), fmaxf(red[2], red[3]));
    rl = rl / rm;
    rela[j] = rl;
    __syncthreads();

    for (int n = wave; n < 264; n += 4) {
        float v = 0.f;
        if (n < 8) {
            #pragma unroll
            for (int i = 0; i < 4; ++i) { int c = lane + 64 * i; v += tanhf(ee[n][c]) * aw[c]; }
        } else {
            int s0 = n - 8;
            const float* row = enc + ((size_t)b * TH + spos[s0]) * 256;
            float rl2 = rela[s0];
            #pragma unroll
            for (int i = 0; i < 4; ++i) { int c = lane + 64 * i; v += tanhf(rl2 * row[c]) * aw[c]; }
        }
        #pragma unroll
        for (int o = 32; o > 0; o >>= 1) v += __shfl_down(v, o);
        if (lane == 0) sc[n] = v;
    }
    __syncthreads();

    float a1 = sc[j];       a1 = (a1 == 0.f) ? -INFINITY : a1;
    float a2 = (j < 8) ? sc[256 + j] : -INFINITY;
    if (a2 == 0.f) a2 = -INFINITY;
    float am = fmaxf(a1, a2);
    #pragma unroll
    for (int o = 32; o > 0; o >>= 1) am = fmaxf(am, __shfl_down(am, o));
    __syncthreads();
    if (lane == 0) red[wave] = am;
    __syncthreads();
    am = fmaxf(fmaxf(red[0], red[1]), fmaxf(red[2], red[3]));
    float e1 = (a1 == -INFINITY) ? 0.f : expf(a1 - am);
    float e2 = (a2 == -INFINITY) ? 0.f : expf(a2 - am);
    float esum = e1 + e2;
    #pragma unroll
    for (int o = 32; o > 0; o >>= 1) esum += __shfl_down(esum, o);
    __syncthreads();
    if (lane == 0) red[wave] = esum;
    __syncthreads();
    esum = red[0] + red[1] + red[2] + red[3];
    __syncthreads();
    sc[j] = e1 / esum;
    if (j < 8) sc[256 + j] = e2 / esum;
    __syncthreads();

    float att = 0.f;
    #pragma unroll
    for (int n = 0; n < 8; ++n) att += sc[n] * ee[n][j];
    for (int s0 = 0; s0 < 256; ++s0) {
        float scn = sc[8 + s0];
        if (scn > 0.f)
            att += scn * rela[s0] * enc[((size_t)b * TH + spos[s0]) * 256 + j];
    }
    float ta = tanhf(att);

    for (int l = 0; l < 19; ++l) {
        float v = ta * dense_W[l * 256 + j];
        #pragma unroll
        for (int o = 32; o > 0; o >>= 1) v += __shfl_down(v, o);
        __syncthreads();
        if (lane == 0) red[wave] = v;
        __syncthreads();
        if (j == 0) out[b * 19 + l] = red[0] + red[1] + red[2] + red[3] + dense_b[l];
    }
}

extern "C" void kernel_launch(void* const* d_in, const int* in_sizes, int n_in,
                              void* d_out, int out_size, void* d_ws, size_t ws_size,
                              hipStream_t stream) {
    (void)in_sizes; (void)n_in; (void)out_size; (void)ws_size;
    const int*   sents        = (const int*)d_in[0];
    const int*   lens         = (const int*)d_in[1];
    const int*   entities     = (const int*)d_in[2];
    const int*   slices       = (const int*)d_in[3];
    const float* slice_lens   = (const float*)d_in[4];
    const int*   entity_masks = (const int*)d_in[5];
    const int*   slice_masks  = (const int*)d_in[6];
    const float* emb          = (const float*)d_in[7];
    const float* Q            = (const float*)d_in[8];
    const float* R            = (const float*)d_in[9];
    const float* Wih_f        = (const float*)d_in[10];
    const float* Whh_f        = (const float*)d_in[11];
    const float* bih_f        = (const float*)d_in[12];
    const float* bhh_f        = (const float*)d_in[13];
    const float* Wih_b        = (const float*)d_in[14];
    const float* Whh_b        = (const float*)d_in[15];
    const float* bih_b        = (const float*)d_in[16];
    const float* bhh_b        = (const float*)d_in[17];
    const float* ent_W        = (const float*)d_in[18];
    const float* ent_b        = (const float*)d_in[19];
    const float* att_w        = (const float*)d_in[20];
    const float* dense_W      = (const float*)d_in[21];
    const float* dense_b      = (const float*)d_in[22];

    // ws: enc [64][512][256] f32 (33.5MB) | Wh 1048576 halfs (2MB)
    float*  enc = (float*)d_ws;
    __half* Wh  = (__half*)(enc + (size_t)Bsz * TH * 256);

    const int smem_bytes = SMEMF * 4;   // 56320 B
    hipFuncSetAttribute(reinterpret_cast<const void*>(scan_k),
                        hipFuncAttributeMaxDynamicSharedMemorySize, smem_bytes);

    hipMemsetAsync(enc, 0, (size_t)Bsz * TH * 256 * sizeof(float), stream);
    pack_k<<<512, 256, 0, stream>>>(Q, R, Wih_f, Whh_f, Wih_b, Whh_b, Wh);
    scan_k<<<64, 512, smem_bytes, stream>>>(sents, lens, emb,
                                            bih_f, bhh_f, bih_b, bhh_b,
                                            Wh, enc);
    epi_k<<<64, 256, 0, stream>>>(enc, entities, slices, slice_lens,
                                  entity_masks, slice_masks, ent_W, ent_b,
                                  att_w, dense_W, dense_b, (float*)d_out);
}

// Round 12
// 11080.596 us; speedup vs baseline: 2.7850x; 1.0337x over previous
//
#include <hip/hip_runtime.h>
#include <hip/hip_fp16.h>
#include <math.h>

typedef unsigned int uint;

#define Bsz 64
#define Tt  1024
#define TH  512      // entities/slices < T/2, lens >= T/2 -> enc only needed for t < 512

// LDS float offsets (half-offsets into smH: xs 0, hcs 512, hms 1024 -> bytes 0..3071)
#define HMF   1280   // float[512] hm2 f32 (for E finalize)
#define PARTF 1792   // 12288 floats (mog 8x512 / gru 8x1536 overlay)
#define SMEMF 14080  // 56320 B

typedef _Float16 h2 __attribute__((ext_vector_type(2)));
#if defined(__has_builtin)
#if __has_builtin(__builtin_amdgcn_fdot2)
#define HAS_FDOT2 1
#endif
#endif

__device__ __forceinline__ float sigm(float x){ return 1.f/(1.f+expf(-x)); }

#define LG0  asm volatile("s_waitcnt lgkmcnt(0)":::"memory")
#define BAR  __builtin_amdgcn_s_barrier

__device__ __forceinline__ void dot2b(uint w, uint a0, uint a1, float& s0, float& s1){
  h2 wh = __builtin_bit_cast(h2, w);
#ifdef HAS_FDOT2
  s0 = __builtin_amdgcn_fdot2(wh, __builtin_bit_cast(h2,a0), s0, false);
  s1 = __builtin_amdgcn_fdot2(wh, __builtin_bit_cast(h2,a1), s1, false);
#else
  h2 x0 = __builtin_bit_cast(h2,a0), x1 = __builtin_bit_cast(h2,a1);
  s0 = fmaf((float)wh.x,(float)x0.x, fmaf((float)wh.y,(float)x0.y, s0));
  s1 = fmaf((float)wh.x,(float)x1.x, fmaf((float)wh.y,(float)x1.y, s1));
#endif
}

// Pack all weights to fp16 in per-(dir,wave) consumption-ordered 4KB units. (R9/R11 layout)
// QH [0,131072) | RH [131072,262144) | GH [262144,1048576) (halfs).
// Q/R unit u (of 4, wave w): cell c<256 = col c, halfs jj<8 = W[32w+8u+jj][c].
// G unit e=u8*3+g (of 24, wave w: mat=w&1, ks=w>>1): cell c = W[g*256+c][64ks+8u8+jj].
__global__ void pack_k(const float* __restrict__ Q, const float* __restrict__ R,
                       const float* __restrict__ Wih_f, const float* __restrict__ Whh_f,
                       const float* __restrict__ Wih_b, const float* __restrict__ Whh_b,
                       __half* __restrict__ Wh)
{
  int ci = blockIdx.x*256 + threadIdx.x;       // 16B cell index, 131072 total
  if (ci >= 131072) return;
  float v[8];
  if (ci < 32768){
    bool isR = ci >= 16384;
    int c0 = ci & 16383;
    int c = c0 & 255;
    int rest = c0 >> 8;                        // (d*8+w)*4+u
    int u = rest & 3, dw = rest >> 2;
    int w = dw & 7, d = dw >> 3;
    const float* S = (isR ? R : Q) + d*65536;  // [k][j]
    int k0 = 32*w + 8*u;
    #pragma unroll
    for (int j=0;j<8;++j) v[j] = S[(k0+j)*256 + c];
  } else {
    int c0 = ci - 32768;                       // 98304 cells
    int c = c0 & 255;
    int rest = c0 >> 8;                        // (d*8+w)*24+e
    int e = rest % 24, dw = rest / 24;
    int w = dw & 7, d = dw >> 3;
    int mat = w & 1, ks = w >> 1;
    int u8 = e / 3, g = e % 3;
    const float* W = mat ? (d? Whh_b : Whh_f) : (d? Wih_b : Wih_f);  // [768][256]
    const float* row = W + (size_t)(g*256 + c)*256 + (64*ks + 8*u8);
    #pragma unroll
    for (int j=0;j<8;++j) v[j] = row[j];
  }
  __half h8[8];
  #pragma unroll
  for (int j=0;j<8;++j) h8[j] = __float2half(v[j]);
  *(uint4*)(Wh + (size_t)ci*8) = *(uint4*)h8;
}

// One WG of 512 threads per (direction, batch-pair), dir grouped per XCD.
// Q/R weight slices live PERMANENTLY in VGPRs (consumed 2x/step each);
// only GRU weights stream, via a 3-deep named-buffer register ring with the
// E-loop fully unrolled (static slots). Carry chain stays f32 in registers.
__global__ __launch_bounds__(512, 1) void scan_k(
    const int* __restrict__ sents, const int* __restrict__ lens,
    const float* __restrict__ emb,
    const float* __restrict__ bih_f, const float* __restrict__ bhh_f,
    const float* __restrict__ bih_b, const float* __restrict__ bhh_b,
    const __half* __restrict__ Wh, float* __restrict__ enc)
{
  extern __shared__ float sm[];
  __half* smH = (__half*)sm;

  const int bx = blockIdx.x;                 // 0..63
  const int dir  = ((bx & 7) >= 4) ? 1 : 0;  // dir constant per XCD residue class
  const int pair = (bx >> 3)*4 + (bx & 3);   // 0..31
  const int b0 = pair*2;
  const int tid = threadIdx.x;
  const int wv = tid >> 6, ln = tid & 63;
  const int cj = tid & 255, cb = tid >> 8;   // finalize (col, batch)
  const int matE = wv & 1, ksE = wv >> 1;    // GRU wave roles

  const __half* QB = Wh + (size_t)((dir*8+wv)*4)*2048;
  const __half* RB = Wh + 131072 + (size_t)((dir*8+wv)*4)*2048;
  const __half* Gp = Wh + 262144 + (size_t)((dir*8+wv)*24)*2048;
  const float* bih = dir ? bih_b : bih_f;
  const float* bhh = dir ? bhh_b : bhh_f;

  const int len0 = lens[b0], len1 = lens[b0+1];
  const int mylen = cb ? len1 : len0;
  const float bi_r = bih[cj], bi_z = bih[cj+256], bi_n = bih[cj+512];
  const float bh_r = bhh[cj], bh_z = bhh[cj+256], bh_n = bhh[cj+512];

  int nsteps, t, tstep;
  if (!dir){ nsteps = TH; t = 0; tstep = 1; }                        // fwd: t<512 observable
  else { int mx = max(len0,len1); nsteps = mx; t = mx-1; tstep = -1; } // bwd: h==0 while masked

  smH[512 + tid] = (__half)0.f;              // hcs zero (512 halfs)

  // ---- persistent Q/R register slices (16 uint4 each) ----
  uint4 Qr[16], Rr[16];
  {
    const uint4* q4 = (const uint4*)QB;
    const uint4* r4 = (const uint4*)RB;
    #pragma unroll
    for (int u=0; u<4; ++u)
      #pragma unroll
      for (int q=0; q<4; ++q){
        Qr[u*4+q] = q4[u*256 + q*64 + ln];
        Rr[u*4+q] = r4[u*256 + q*64 + ln];
      }
  }

  auto dot4 = [&](const uint4& W, const uint4& A0, const uint4& A1, float& a0, float& a1){
    dot2b(W.x, A0.x, A1.x, a0, a1);
    dot2b(W.y, A0.y, A1.y, a0, a1);
    dot2b(W.z, A0.z, A1.z, a0, a1);
    dot2b(W.w, A0.w, A1.w, a0, a1);
  };

  // mog phase from register weights
  auto mog_part = [&](int actsHO, const uint4 (&W)[16]){
    float2 acc[4];
    acc[0]=acc[1]=acc[2]=acc[3]=make_float2(0.f,0.f);
    #pragma unroll
    for (int u=0; u<4; ++u){
      const int k8 = 4*wv + u;
      const uint4 a0 = *(const uint4*)(smH + actsHO + k8*8);
      const uint4 a1 = *(const uint4*)(smH + actsHO + 256 + k8*8);
      dot4(W[u*4+0], a0, a1, acc[0].x, acc[0].y);
      dot4(W[u*4+1], a0, a1, acc[1].x, acc[1].y);
      dot4(W[u*4+2], a0, a1, acc[2].x, acc[2].y);
      dot4(W[u*4+3], a0, a1, acc[3].x, acc[3].y);
    }
    #pragma unroll
    for (int q=0;q<4;++q)
      *(float2*)(sm + PARTF + wv*512 + (ln+64*q)*2) = acc[q];
  };
  // finalize mog (thread = (cj,cb)): sum 8 partials, gate, store fp16 (+opt f32) act.
  auto mog_fin = [&](float mult, int dstHO, bool alsoF32)->float{
    float ssum = 0.f;
    #pragma unroll
    for (int p=0;p<8;++p) ssum += sm[PARTF + p*512 + cj*2 + cb];
    float val = 2.f*sigm(ssum)*mult;
    smH[dstHO + cb*256 + cj] = (__half)val;
    if (alsoF32) sm[HMF + cb*256 + cj] = val;
    return val;
  };

  // ---- 3-deep G ring (named buffers, static slots) ----
  uint4 GA[4], GBb[4], GC[4];
  #define LDU(DST, U) do{ const uint4* p_ = (const uint4*)(Gp + (size_t)(U)*2048); \
    DST[0]=p_[ln]; DST[1]=p_[ln+64]; DST[2]=p_[ln+128]; DST[3]=p_[ln+192]; }while(0)
  LDU(GA, 0); LDU(GBb, 1);                   // prime units 0,1

  float hprev = 0.f, x1 = 0.f, hm1 = 0.f;
  LG0; BAR();

  for (int s=0; s<nsteps; ++s, t+=tstep){
    int tok = sents[(b0+cb)*Tt + t];
    float x0 = emb[(size_t)tok*256 + cj];

    // A: x1 = 2sig(h@Q)*x0
    mog_part(512, Qr);              LG0; BAR();
    x1 = mog_fin(x0, 0, false);     LG0; BAR();
    // B: hm1 = 2sig(x1@R)*h
    mog_part(0, Rr);                LG0; BAR();
    hm1 = mog_fin(hprev, 1024, false); LG0; BAR();
    // C: x2 = 2sig(hm1@Q)*x1
    mog_part(1024, Qr);             LG0; BAR();
    x1 = mog_fin(x1, 0, false);     LG0; BAR();      // x1 now holds x2
    // D: hm2 = 2sig(x2@R)*hm1
    mog_part(0, Rr);                LG0; BAR();
    mog_fin(hm1, 1024, true);       LG0; BAR();

    // E: GRU — fully unrolled 24 units, ring slots A,B,C (unit%3).
    {
      const int AFh = matE ? 1024 : 0;
      float2 ag[12];
      #pragma unroll
      for (int i=0;i<12;++i) ag[i] = make_float2(0.f,0.f);

      #define E_STEP(E, CUR, NXT, NU) { \
        LDU(NXT, NU); \
        const int u8_ = (E)/3, g_ = (E) - 3*u8_; \
        const int kb_ = 64*ksE + 8*u8_; \
        const uint4 ea0 = *(const uint4*)(smH + AFh + kb_); \
        const uint4 ea1 = *(const uint4*)(smH + AFh + 256 + kb_); \
        dot4(CUR[0], ea0, ea1, ag[g_*4+0].x, ag[g_*4+0].y); \
        dot4(CUR[1], ea0, ea1, ag[g_*4+1].x, ag[g_*4+1].y); \
        dot4(CUR[2], ea0, ea1, ag[g_*4+2].x, ag[g_*4+2].y); \
        dot4(CUR[3], ea0, ea1, ag[g_*4+3].x, ag[g_*4+3].y); }

      E_STEP(0,  GA,  GC,  2);  E_STEP(1,  GBb, GA,  3);  E_STEP(2,  GC,  GBb, 4);
      E_STEP(3,  GA,  GC,  5);  E_STEP(4,  GBb, GA,  6);  E_STEP(5,  GC,  GBb, 7);
      E_STEP(6,  GA,  GC,  8);  E_STEP(7,  GBb, GA,  9);  E_STEP(8,  GC,  GBb, 10);
      E_STEP(9,  GA,  GC,  11); E_STEP(10, GBb, GA,  12); E_STEP(11, GC,  GBb, 13);
      E_STEP(12, GA,  GC,  14); E_STEP(13, GBb, GA,  15); E_STEP(14, GC,  GBb, 16);
      E_STEP(15, GA,  GC,  17); E_STEP(16, GBb, GA,  18); E_STEP(17, GC,  GBb, 19);
      E_STEP(18, GA,  GC,  20); E_STEP(19, GBb, GA,  21); E_STEP(20, GC,  GBb, 22);
      E_STEP(21, GA,  GC,  23); E_STEP(22, GBb, GA,  0);  E_STEP(23, GC,  GBb, 1);
      #undef E_STEP

      #pragma unroll
      for (int g=0;g<3;++g)
        #pragma unroll
        for (int q=0;q<4;++q)
          *(float2*)(sm + PARTF + wv*1536 + (g*256 + ln + 64*q)*2) = ag[g*4+q];
    }
    LG0; BAR();
    // finalize GRU: thread (cj, cb)
    {
      float gi[3], gh[3];
      #pragma unroll
      for (int g=0; g<3; ++g){
        float si = 0.f, sh = 0.f;
        #pragma unroll
        for (int p=0;p<4;++p){
          si += sm[PARTF + (p*2+0)*1536 + (g*256+cj)*2 + cb];
          sh += sm[PARTF + (p*2+1)*1536 + (g*256+cj)*2 + cb];
        }
        gi[g] = si; gh[g] = sh;
      }
      float r = sigm(gi[0]+bi_r + gh[0]+bh_r);
      float z = sigm(gi[1]+bi_z + gh[1]+bh_z);
      float n = tanhf(gi[2]+bi_n + r*(gh[2]+bh_n));
      float hm2v = sm[HMF + cb*256 + cj];
      float uu = (1.f - z)*n + z*hm2v;
      bool m = (t < mylen);
      float hnew = m ? uu : hprev;
      hprev = hnew;
      smH[512 + cb*256 + cj] = (__half)hnew;
      if (m && t < TH)
        atomicAdd(&enc[((size_t)(b0+cb)*TH + t)*256 + cj], uu);
    }
    LG0; BAR();
  }
  #undef LDU
}

// One WG per batch element. Reproduces gate_attention + attention + dense exactly.
__global__ __launch_bounds__(256) void epi_k(
    const float* __restrict__ enc,
    const int* __restrict__ entities, const int* __restrict__ slices,
    const float* __restrict__ slice_lens,
    const int* __restrict__ entity_masks, const int* __restrict__ slice_masks,
    const float* __restrict__ ent_W, const float* __restrict__ ent_b,
    const float* __restrict__ att_w,
    const float* __restrict__ dense_W, const float* __restrict__ dense_b,
    float* __restrict__ out)
{
    const int b = blockIdx.x;
    const int j = threadIdx.x;
    const int wave = j >> 6, lane = j & 63;

    __shared__ float ee[8][256];
    __shared__ float p[256];
    __shared__ float rela[256];
    __shared__ float sc[264];
    __shared__ float red[4];
    __shared__ float aw[256];
    __shared__ int   spos[256];

    aw[j]   = att_w[j];
    spos[j] = slices[b * 256 + j];
    #pragma unroll
    for (int e = 0; e < 8; ++e)
        ee[e][j] = enc[((size_t)b * TH + entities[b * 8 + e]) * 256 + j];
    __syncthreads();

    float entWj = ent_W[j];
    for (int e = 0; e < 8; ++e) {
        float v = ee[e][j] * entWj;
        #pragma unroll
        for (int o = 32; o > 0; o >>= 1) v += __shfl_down(v, o);
        if (lane == 0) red[wave] = v;
        __syncthreads();
        if (j == 0) sc[e] = red[0] + red[1] + red[2] + red[3] + ent_b[0];
        __syncthreads();
    }
    float mx = -INFINITY;
    float ewv[8];
    #pragma unroll
    for (int e = 0; e < 8; ++e) {
        float v = entity_masks[b * 8 + e] ? sc[e] : -INFINITY;
        ewv[e] = v; mx = fmaxf(mx, v);
    }
    float den = 0.f;
    #pragma unroll
    for (int e = 0; e < 8; ++e) {
        ewv[e] = entity_masks[b * 8 + e] ? expf(ewv[e] - mx) : 0.f;
        den += ewv[e];
    }
    float accp = 0.f;
    #pragma unroll
    for (int e = 0; e < 8; ++e) accp += (ewv[e] / den) * ee[e][j];
    p[j] = tanhf(accp);
    __syncthreads();

    for (int s0 = wave; s0 < 256; s0 += 4) {
        const float* row = enc + ((size_t)b * TH + spos[s0]) * 256;
        float v = 0.f;
        #pragma unroll
        for (int i = 0; i < 4; ++i) { int c = lane + 64 * i; v += row[c] * p[c]; }
        #pragma unroll
        for (int o = 32; o > 0; o >>= 1) v += __shfl_down(v, o);
        if (lane == 0) sc[s0] = v;
    }
    __syncthreads();

    float sl  = slice_lens[b];
    int   smk = slice_masks[b * 256 + j];
    float wv  = smk ? sc[j] : -INFINITY;
    float bm = wv;
    #pragma unroll
    for (int o = 32; o > 0; o >>= 1) bm = fmaxf(bm, __shfl_down(bm, o));
    __syncthreads();
    if (lane == 0) red[wave] = bm;
    __syncthreads();
    bm = fmaxf(fmaxf(red[0], red[1]), fmaxf(red[2], red[3]));
    float ex = smk ? expf(wv - bm) : 0.f;
    float sm2 = ex;
    #pragma unroll
    for (int o = 32; o > 0; o >>= 1) sm2 += __shfl_down(sm2, o);
    __syncthreads();
    if (lane == 0) red[wave] = sm2;
    __syncthreads();
    sm2 = red[0] + red[1] + red[2] + red[3];
    float ww = ex / sm2 * sl;
    float rl = (ww > 0.05f) ? (ww / sl) : 0.f;   // BETA = 0.05
    float rm = rl;
    #pragma unroll
    for (int o = 32; o > 0; o >>= 1) rm = fmaxf(rm, __shfl_down(rm, o));
    __syncthreads();
    if (lane == 0) red[wave] = rm;
    __syncthreads();
    rm = fmaxf(fmaxf(red[0], red[1]), fmaxf(red[2], red[3]));
    rl = rl / rm;
    rela[j] = rl;
    __syncthreads();

    for (int n = wave; n < 264; n += 4) {
        float v = 0.f;
        if (n < 8) {
            #pragma unroll
            for (int i = 0; i < 4; ++i) { int c = lane + 64 * i; v += tanhf(ee[n][c]) * aw[c]; }
        } else {
            int s0 = n - 8;
            const float* row = enc + ((size_t)b * TH + spos[s0]) * 256;
            float rl2 = rela[s0];
            #pragma unroll
            for (int i = 0; i < 4; ++i) { int c = lane + 64 * i; v += tanhf(rl2 * row[c]) * aw[c]; }
        }
        #pragma unroll
        for (int o = 32; o > 0; o >>= 1) v += __shfl_down(v, o);
        if (lane == 0) sc[n] = v;
    }
    __syncthreads();

    float a1 = sc[j];       a1 = (a1 == 0.f) ? -INFINITY : a1;
    float a2 = (j < 8) ? sc[256 + j] : -INFINITY;
    if (a2 == 0.f) a2 = -INFINITY;
    float am = fmaxf(a1, a2);
    #pragma unroll
    for (int o = 32; o > 0; o >>= 1) am = fmaxf(am, __shfl_down(am, o));
    __syncthreads();
    if (lane == 0) red[wave] = am;
    __syncthreads();
    am = fmaxf(fmaxf(red[0], red[1]), fmaxf(red[2], red[3]));
    float e1 = (a1 == -INFINITY) ? 0.f : expf(a1 - am);
    float e2 = (a2 == -INFINITY) ? 0.f : expf(a2 - am);
    float esum = e1 + e2;
    #pragma unroll
    for (int o = 32; o > 0; o >>= 1) esum += __shfl_down(esum, o);
    __syncthreads();
    if (lane == 0) red[wave] = esum;
    __syncthreads();
    esum = red[0] + red[1] + red[2] + red[3];
    __syncthreads();
    sc[j] = e1 / esum;
    if (j < 8) sc[256 + j] = e2 / esum;
    __syncthreads();

    float att = 0.f;
    #pragma unroll
    for (int n = 0; n < 8; ++n) att += sc[n] * ee[n][j];
    for (int s0 = 0; s0 < 256; ++s0) {
        float scn = sc[8 + s0];
        if (scn > 0.f)
            att += scn * rela[s0] * enc[((size_t)b * TH + spos[s0]) * 256 + j];
    }
    float ta = tanhf(att);

    for (int l = 0; l < 19; ++l) {
        float v = ta * dense_W[l * 256 + j];
        #pragma unroll
        for (int o = 32; o > 0; o >>= 1) v += __shfl_down(v, o);
        __syncthreads();
        if (lane == 0) red[wave] = v;
        __syncthreads();
        if (j == 0) out[b * 19 + l] = red[0] + red[1] + red[2] + red[3] + dense_b[l];
    }
}

extern "C" void kernel_launch(void* const* d_in, const int* in_sizes, int n_in,
                              void* d_out, int out_size, void* d_ws, size_t ws_size,
                              hipStream_t stream) {
    (void)in_sizes; (void)n_in; (void)out_size; (void)ws_size;
    const int*   sents        = (const int*)d_in[0];
    const int*   lens         = (const int*)d_in[1];
    const int*   entities     = (const int*)d_in[2];
    const int*   slices       = (const int*)d_in[3];
    const float* slice_lens   = (const float*)d_in[4];
    const int*   entity_masks = (const int*)d_in[5];
    const int*   slice_masks  = (const int*)d_in[6];
    const float* emb          = (const float*)d_in[7];
    const float* Q            = (const float*)d_in[8];
    const float* R            = (const float*)d_in[9];
    const float* Wih_f        = (const float*)d_in[10];
    const float* Whh_f        = (const float*)d_in[11];
    const float* bih_f        = (const float*)d_in[12];
    const float* bhh_f        = (const float*)d_in[13];
    const float* Wih_b        = (const float*)d_in[14];
    const float* Whh_b        = (const float*)d_in[15];
    const float* bih_b        = (const float*)d_in[16];
    const float* bhh_b        = (const float*)d_in[17];
    const float* ent_W        = (const float*)d_in[18];
    const float* ent_b        = (const float*)d_in[19];
    const float* att_w        = (const float*)d_in[20];
    const float* dense_W      = (const float*)d_in[21];
    const float* dense_b      = (const float*)d_in[22];

    // ws: enc [64][512][256] f32 (33.5MB) | Wh 1048576 halfs (2MB)
    float*  enc = (float*)d_ws;
    __half* Wh  = (__half*)(enc + (size_t)Bsz * TH * 256);

    const int smem_bytes = SMEMF * 4;   // 56320 B
    hipFuncSetAttribute(reinterpret_cast<const void*>(scan_k),
                        hipFuncAttributeMaxDynamicSharedMemorySize, smem_bytes);

    hipMemsetAsync(enc, 0, (size_t)Bsz * TH * 256 * sizeof(float), stream);
    pack_k<<<512, 256, 0, stream>>>(Q, R, Wih_f, Whh_f, Wih_b, Whh_b, Wh);
    scan_k<<<64, 512, smem_bytes, stream>>>(sents, lens, emb,
                                            bih_f, bhh_f, bih_b, bhh_b,
                                            Wh, enc);
    epi_k<<<64, 256, 0, stream>>>(enc, entities, slices, slice_lens,
                                  entity_masks, slice_masks, ent_W, ent_b,
                                  att_w, dense_W, dense_b, (float*)d_out);
}